// Round 17
// baseline (297.849 us; speedup 1.0000x reference)
//
#include <hip/hip_runtime.h>
#include <hip/hip_bf16.h>

typedef __attribute__((ext_vector_type(4))) float f32x4;
typedef __attribute__((ext_vector_type(4))) unsigned u32x4;
typedef __attribute__((ext_vector_type(8))) short short8;

#define NB 16384
#define ND 32
#define NK 128

// pack 2 f32 -> 1 u32 of 2 bf16 (RTNE) via v_cvt_pk_bf16_f32
__device__ __forceinline__ unsigned pk2(float lo, float hi){
  float2 f; f.x = lo; f.y = hi;
  __hip_bfloat162 h = __float22bfloat162_rn(f);
  union { __hip_bfloat162 h; unsigned u; } v; v.h = h;
  return v.u;
}

// ---------------------------------------------------------------------------
// Kernel 1 (v12, MFMA @ 2 blocks/CU): per-cluster scatter M_k = X_k X_k^T
// (full 32x32) + column sums S.
// grid = 512 (XCD-swizzled: ktile 0..3, cb 0..127 -> 128 samples), block 512.
// vs r16: occupancy 1 -> 2 blocks/CU (r4/r12 counters: latency-bound,
// nothing saturated, 10.9% occ).  (1) grid 512 via k3's bijective swizzle
// (ktile granule-pairs (2p,2p+1) same XCD); (2) VGPR <= 128 via half-batch
// staging (4 sample-pairs in flight = 32 regs) + launch_bounds(512,4);
// (3) LDS 64 KB (ssr reuses vs after last MFMA barrier) -> 128 KB/CU for 2.
// Slot layout per (k,d) byte-identical to r16's validated mapping.
// Partials: part[cb][k][1056] (1024 M + 32 S), plain stores (L3-resident).
// ---------------------------------------------------------------------------
__global__ __launch_bounds__(512, 4) void k1_scatter(const float* __restrict__ x,
                                                     float* __restrict__ part) {
  __shared__ float vs[16384];        // 32 clusters x 512 u32 = 64 KB
  const int t = threadIdx.x;
  const int bx = blockIdx.x;         // 0..511
  const int m  = (bx >> 3) & 1;
  const int u  = ((bx >> 4) << 3) | (bx & 7);
  const int ktile = ((u & 1) << 1) | m;    // 0..3 (pairs share XCD)
  const int cb    = u >> 1;                // 0..127
  const int k0 = ktile*32;

  // staging decomposition: t -> (shalf, d, kq)
  const int shalf = t >> 8;          // 0..1  (which 16-sample half)
  const int d     = (t >> 3) & 31;   // 0..31
  const int kq    = t & 7;           // k-quad 0..7
  const float* xb = x + (size_t)d*128 + k0 + 4*kq;

  // compute decomposition: lane l, wave w
  const int l = t & 63;
  const int w = t >> 6;              // 0..7

  f32x4 acc[4][4];                   // [cluster][tile i*2+j]
  #pragma unroll
  for (int c=0;c<4;c++)
    #pragma unroll
    for (int q=0;q<4;q++){ acc[c][q][0]=0.f; acc[c][q][1]=0.f; acc[c][q][2]=0.f; acc[c][q][3]=0.f; }
  float ssum[4] = {0.f,0.f,0.f,0.f};

  unsigned* vsw = (unsigned*)vs;

  for (int ch = 0; ch < 4; ++ch) {
    const int sb = cb*128 + ch*32 + shalf*16;
    // ---- stage in two half-batches of 4 sample-pairs (32 load-regs peak)
    #pragma unroll
    for (int h = 0; h < 2; ++h) {
      f32x4 La[4], Lb[4];
      #pragma unroll
      for (int p = 0; p < 4; ++p) {
        const float* src = xb + (size_t)(sb + 2*(4*h + p))*4096;
        La[p] = *(const f32x4*)src;
        Lb[p] = *(const f32x4*)(src + 4096);
      }
      #pragma unroll
      for (int i = 0; i < 4; ++i) {
        unsigned w4[4];
        #pragma unroll
        for (int p = 0; p < 4; ++p) {
          w4[p] = pk2(La[p][i], Lb[p][i]);
          ssum[i] += La[p][i] + Lb[p][i];
        }
        const int c = (kq + i) & 3;
        const int o = (shalf*8 + 4*h + 4*c) & 15;  // 4-aligned, no wrap
        unsigned* rowp = vsw + (4*kq + i)*512 + d*16;
        u32x4 q4 = { w4[0], w4[1], w4[2], w4[3] };
        *(u32x4*)(rowp + o) = q4;
      }
    }
    __syncthreads();
    // ---- MFMA: 4 clusters per wave, slot-group offset (w+c)&3
    #pragma unroll
    for (int c = 0; c < 4; ++c) {
      const int kk = w*4 + c;
      const float* base = vs + kk*512;
      const int sg = 4*(((l>>4) + w + c) & 3);
      const short8 f0 = *(const short8*)(base + (l&15)*16       + sg);
      const short8 f1 = *(const short8*)(base + (l&15)*16 + 256 + sg);
      acc[c][0] = __builtin_amdgcn_mfma_f32_16x16x32_bf16(f0, f0, acc[c][0], 0,0,0);
      acc[c][1] = __builtin_amdgcn_mfma_f32_16x16x32_bf16(f0, f1, acc[c][1], 0,0,0);
      acc[c][2] = __builtin_amdgcn_mfma_f32_16x16x32_bf16(f1, f0, acc[c][2], 0,0,0);
      acc[c][3] = __builtin_amdgcn_mfma_f32_16x16x32_bf16(f1, f1, acc[c][3], 0,0,0);
    }
    __syncthreads();
  }

  // ---- epilogue: M tiles.  C/D layout col = l&15, row = (l>>4)*4 + reg.
  const int col = l & 15, rw = (l >> 4) * 4;
  #pragma unroll
  for (int c = 0; c < 4; ++c) {
    const int kg = k0 + w*4 + c;
    float* pb = part + ((size_t)cb*128 + kg)*1056;
    #pragma unroll
    for (int i = 0; i < 2; ++i)
      #pragma unroll
      for (int j = 0; j < 2; ++j)
        #pragma unroll
        for (int r = 0; r < 4; ++r)
          pb[(i*16 + rw + r)*32 + j*16 + col] = acc[c][i*2+j][r];
  }
  // ---- S: reuse vs (dead after last barrier) as [shalf][d][k] reduce buf
  #pragma unroll
  for (int i = 0; i < 4; ++i)
    vs[shalf*1024 + d*32 + 4*kq + i] = ssum[i];
  __syncthreads();
  for (int ii = t; ii < 1024; ii += 512) {
    const int dd = ii >> 5, kk2 = ii & 31;
    part[((size_t)cb*128 + k0 + kk2)*1056 + 1024 + dd] = vs[ii] + vs[1024 + ii];
  }
}

// ---------------------------------------------------------------------------
// Kernel 2a: reduce partials over 128 chunk-blocks.  grid 528 x 256.
// part[cb][135168], contiguous outputs -> fully coalesced; L3/L2-resident.
// out sfin[135168] = [128 k][1056]
// ---------------------------------------------------------------------------
__global__ void k2a_reduce(const float* __restrict__ part, float* __restrict__ sfin) {
  const size_t idx = (size_t)blockIdx.x*256 + threadIdx.x;   // 0..135167
  const float* p = part + idx;
  float a0=0.f,a1=0.f,a2=0.f,a3=0.f;
  for (int c = 0; c < 128; c += 4) {
    a0 += p[(size_t)(c+0)*135168];
    a1 += p[(size_t)(c+1)*135168];
    a2 += p[(size_t)(c+2)*135168];
    a3 += p[(size_t)(c+3)*135168];
  }
  sfin[idx] = (a0+a1)+(a2+a3);
}

// ---------------------------------------------------------------------------
// Kernel 2b: per-cluster cov assembly + Cholesky.  grid 128, block 256.
// sfin[k][1056]: M (full 32x32) at d*32+e, S at 1024+d.
// ---------------------------------------------------------------------------
__global__ void k2b_chol(const float* __restrict__ sfin,
                         const float* __restrict__ mu0,
                         const float* __restrict__ L0,
                         const float* __restrict__ n0p,
                         float* __restrict__ lpad,
                         float* __restrict__ nmu) {
  const int k = blockIdx.x;
  const int t = threadIdx.x;
  __shared__ float L0s[32*33];
  __shared__ float Am[32*33];
  __shared__ float xdl[32];
  __shared__ float dinv[32];
  const float n0 = n0p[0];
  const float denom = n0 + (float)NB;
  const float* sk = sfin + (size_t)k*1056;

  for (int idx = t; idx < 1024; idx += 256)
    L0s[(idx>>5)*33 + (idx&31)] = L0[k*1024 + idx];
  if (t < 32) {
    const float S  = sk[1024 + t];
    const float m0 = mu0[t*128 + k];
    nmu[t*128 + k] = (n0*m0 + S) / denom;          // B*x_mu == S
    xdl[t] = S*(1.0f/NB) - m0;
  }
  __syncthreads();

  const float c1 = n0/denom, c2 = 1.0f/denom;
  const float c3 = n0*(float)NB/(denom*denom);
  for (int idx = t; idx < 1024; idx += 256) {
    const int d = idx>>5, e = idx&31;
    const float M  = sk[d*32 + e];
    const float Sd = sk[1024 + d];
    const float Se = sk[1024 + e];
    const float C = M - Sd*Se*(1.0f/NB);
    float g = 0.f;
    #pragma unroll 8
    for (int f=0; f<32; f++) g += L0s[d*33+f]*L0s[e*33+f];
    float a = g*c1 + C*c2 + xdl[d]*xdl[e]*c3;
    if (d==e) a += 1.0f;
    Am[d*33+e] = a;
  }
  __syncthreads();

  for (int j=0;j<32;j++){
    float acc = 0.f;
    if (t < 32 && t >= j) {
      acc = Am[t*33+j];
      for (int e=0;e<j;e++) acc -= Am[t*33+e]*Am[j*33+e];
    }
    __syncthreads();
    if (t == j) {
      const float dj = sqrtf(acc);
      Am[j*33+j] = dj;
      dinv[j] = 1.0f/dj;
    }
    __syncthreads();
    if (t < 32 && t > j) Am[t*33+j] = acc*dinv[j];
    __syncthreads();
  }

  if (t < 32) {
    const int d = t;
    int rs = 0;
    for (int e=0;e<d;e++) rs += (e+3)>>2;
    rs *= 4;
    const int rl = ((d+3)>>2)*4;
    float* lp = lpad + k*576;
    for (int e=0;e<rl;e++) lp[rs+e] = (e<d) ? Am[d*33+e] : 0.f;
    lp[544+d] = dinv[d];
  }
}

// ---------------------------------------------------------------------------
// Kernel 3 (frozen since r4, ~72us at HBM roofline): whitening solve
// z = L^{-1}(x - mu').  grid 512, block 256.  Full-128B-line accesses;
// XCD swizzle pairs ktiles (2p,2p+1) on the same XCD; NT output stores.
// ---------------------------------------------------------------------------
__global__ __launch_bounds__(256, 2) void k3_whiten(const float* __restrict__ x,
                                                    const float* __restrict__ lpad,
                                                    const float* __restrict__ nmu,
                                                    float* __restrict__ out) {
  __shared__ float Lw[32*580];   // 32 k-rows, stride 580 (16B-aligned, mod32==4)
  __shared__ float muL[32*32];   // [d][kl]
  const int t = threadIdx.x;
  const int bx = blockIdx.x;     // 0..511
  const int m = (bx >> 3) & 1;
  const int u = ((bx >> 4) << 3) | (bx & 7);   // 0..255
  const int ktile = ((u & 1) << 1) | m;        // 2p + m
  const int chunk = u >> 1;                    // 0..127
  const int k0 = ktile*32;

  {
    const f32x4* src = (const f32x4*)(lpad + (size_t)k0*576);
    #pragma unroll
    for (int q=0;q<18;q++){
      const int idx = t + q*256;        // 4608 f32x4 = 32 rows x 144
      const int row = idx/144, col = idx - row*144;
      *(f32x4*)(&Lw[row*580 + col*4]) = src[idx];
    }
    #pragma unroll
    for (int idx=t; idx<1024; idx+=256)
      muL[idx] = nmu[(idx>>5)*128 + k0 + (idx&31)];
  }
  __syncthreads();

  const int kl = t & 31;
  const int so = t >> 5;          // 0..7 sample slot
  const float* Lrow = &Lw[kl*580];
  const int b0 = chunk*128;

  for (int it=0; it<4; ++it) {
    const int base = b0 + it*32 + so;
    const float* xa = x + (size_t)(base     )*4096 + k0 + kl;
    const float* xb = x + (size_t)(base +  8)*4096 + k0 + kl;
    const float* xc = x + (size_t)(base + 16)*4096 + k0 + kl;
    const float* xd = x + (size_t)(base + 24)*4096 + k0 + kl;
    float vA[32], vB[32], vC[32], vD[32];
    #pragma unroll
    for (int d=0; d<32; ++d) vA[d] = xa[d*128];
    #pragma unroll
    for (int d=0; d<32; ++d) vB[d] = xb[d*128];
    #pragma unroll
    for (int d=0; d<32; ++d) vC[d] = xc[d*128];
    #pragma unroll
    for (int d=0; d<32; ++d) vD[d] = xd[d*128];
    #pragma unroll
    for (int d=0; d<32; ++d) {
      const float m2 = muL[d*32 + kl];
      vA[d] -= m2; vB[d] -= m2; vC[d] -= m2; vD[d] -= m2;
    }
    int rs = 0;
    #pragma unroll
    for (int d=0; d<32; ++d) {
      float sA = vA[d], sB = vB[d], sC = vC[d], sD = vD[d];
      const int nq = (d+3)>>2;
      #pragma unroll
      for (int q=0; q<nq; ++q) {
        const f32x4 Lq = *(const f32x4*)(Lrow + rs + 4*q);
        sA -= Lq[0]*vA[4*q+0] + Lq[1]*vA[4*q+1] + Lq[2]*vA[4*q+2] + Lq[3]*vA[4*q+3];
        sB -= Lq[0]*vB[4*q+0] + Lq[1]*vB[4*q+1] + Lq[2]*vB[4*q+2] + Lq[3]*vB[4*q+3];
        sC -= Lq[0]*vC[4*q+0] + Lq[1]*vC[4*q+1] + Lq[2]*vC[4*q+2] + Lq[3]*vC[4*q+3];
        sD -= Lq[0]*vD[4*q+0] + Lq[1]*vD[4*q+1] + Lq[2]*vD[4*q+2] + Lq[3]*vD[4*q+3];
      }
      const float di = Lrow[544+d];
      vA[d] = sA*di; vB[d] = sB*di; vC[d] = sC*di; vD[d] = sD*di;
      rs += 4*nq;
    }
    float* oa = out + (size_t)(base     )*4096 + k0 + kl;
    float* ob = out + (size_t)(base +  8)*4096 + k0 + kl;
    float* oc = out + (size_t)(base + 16)*4096 + k0 + kl;
    float* od = out + (size_t)(base + 24)*4096 + k0 + kl;
    #pragma unroll
    for (int d=0; d<32; ++d) __builtin_nontemporal_store(vA[d], oa + d*128);
    #pragma unroll
    for (int d=0; d<32; ++d) __builtin_nontemporal_store(vB[d], ob + d*128);
    #pragma unroll
    for (int d=0; d<32; ++d) __builtin_nontemporal_store(vC[d], oc + d*128);
    #pragma unroll
    for (int d=0; d<32; ++d) __builtin_nontemporal_store(vD[d], od + d*128);
  }
}

// ---------------------------------------------------------------------------
extern "C" void kernel_launch(void* const* d_in, const int* in_sizes, int n_in,
                              void* d_out, int out_size, void* d_ws, size_t ws_size,
                              hipStream_t stream) {
  const float* x   = (const float*)d_in[0];
  const float* mu0 = (const float*)d_in[1];
  const float* L0  = (const float*)d_in[2];
  const float* n0  = (const float*)d_in[3];
  float* out  = (float*)d_out;
  float* part = out;                    // [128][128][1056] = 17,301,504 floats (scratch in d_out)
  float* sfin = out + 17301504;         // [128][1056]      =    135,168 floats (scratch in d_out)
  float* lpad = (float*)d_ws;           // [128][576]
  float* nmu  = lpad + 128*576;         // [32][128]

  k1_scatter<<<512, 512, 0, stream>>>(x, part);
  k2a_reduce<<<528, 256, 0, stream>>>(part, sfin);
  k2b_chol  <<<128, 256, 0, stream>>>(sfin, mu0, L0, n0, lpad, nmu);
  k3_whiten <<<512, 256, 0, stream>>>(x, lpad, nmu, out);
}

// Round 18
// 194.328 us; speedup vs baseline: 1.5327x; 1.5327x over previous
//
#include <hip/hip_runtime.h>
#include <hip/hip_bf16.h>

typedef __attribute__((ext_vector_type(4))) float f32x4;
typedef __attribute__((ext_vector_type(4))) unsigned u32x4;
typedef __attribute__((ext_vector_type(8))) short short8;

#define NB 16384
#define ND 32
#define NK 128

// pack 2 f32 -> 1 u32 of 2 bf16 (RTNE) via v_cvt_pk_bf16_f32
__device__ __forceinline__ unsigned pk2(float lo, float hi){
  float2 f; f.x = lo; f.y = hi;
  __hip_bfloat162 h = __float22bfloat162_rn(f);
  union { __hip_bfloat162 h; unsigned u; } v; v.h = h;
  return v.u;
}

// ---------------------------------------------------------------------------
// Kernel 1 (v11 = r16 best, reverted from r17's spill-regression):
// per-cluster scatter M_k = X_k X_k^T (full 32x32) + column sums S via bf16
// MFMA 16x16x32.  grid = 256 (ktile = bx&3 -> 32 k, cb = bx>>2 -> 256
// samples), block = 512, NO launch_bounds VGPR squeeze (r17's (512,4) forced
// VGPR=64 -> ~200MB spill traffic, k1 160us).
// bf16 pack via v_cvt_pk_bf16_f32 (1 inst/pair); LDS staging as 2x
// ds_write_b128 per (k,d); loads coalesced (instr = 8 x 128B full lines);
// chunk g+1 prefetched during g's MFMA phase; S via staging-side adds +
// 8KB LDS reduce.  Slot layout: (k,d,sp) at slot (sp + 4*((kq+i)&3))&15;
// reader applies wave-uniform group offset (w+c)&3 (K-permutation harmless:
// both MFMA operands read identically).
// Partials: part[cb][k][1056] (1024 M + 32 S), plain stores (L3-resident).
// ---------------------------------------------------------------------------
__global__ __launch_bounds__(512, 2) void k1_scatter(const float* __restrict__ x,
                                                     float* __restrict__ part) {
  __shared__ float vs[16384];        // 32 clusters x 512 u32 = 64 KB
  __shared__ float ssr[2048];        // [shalf][d][k] S-reduce, 8 KB
  const int t = threadIdx.x;
  const int bx = blockIdx.x;         // 0..255
  const int ktile = bx & 3;
  const int cb = bx >> 2;            // 0..63
  const int k0 = ktile*32;

  // staging decomposition: t -> (shalf, d, kq)
  const int shalf = t >> 8;          // 0..1  (which 16-sample half)
  const int d     = (t >> 3) & 31;   // 0..31
  const int kq    = t & 7;           // k-quad 0..7
  const float* xb = x + (size_t)d*128 + k0 + 4*kq;

  // compute decomposition: lane l, wave w
  const int l = t & 63;
  const int w = t >> 6;              // 0..7

  f32x4 acc[4][4];                   // [cluster][tile i*2+j]
  #pragma unroll
  for (int c=0;c<4;c++)
    #pragma unroll
    for (int q=0;q<4;q++){ acc[c][q][0]=0.f; acc[c][q][1]=0.f; acc[c][q][2]=0.f; acc[c][q][3]=0.f; }
  float ssum[4] = {0.f,0.f,0.f,0.f};

  unsigned* vsw = (unsigned*)vs;
  f32x4 La[8], Lb[8];

  // prologue: load chunk 0 (coalesced: instr = 8 lanes x 16B contiguous per d)
  {
    const int sb = cb*256 + shalf*16;
    #pragma unroll
    for (int p = 0; p < 8; ++p) {
      const float* src = xb + (size_t)(sb + 2*p)*4096;
      La[p] = *(const f32x4*)src;
      Lb[p] = *(const f32x4*)(src + 4096);
    }
  }

  #pragma unroll
  for (int ch = 0; ch < 8; ++ch) {
    // ---- stage current chunk: cvt_pk pack + 2x b128 LDS write per (k,d)
    #pragma unroll
    for (int i = 0; i < 4; ++i) {
      unsigned w8[8];
      #pragma unroll
      for (int p = 0; p < 8; ++p) {
        w8[p] = pk2(La[p][i], Lb[p][i]);
        ssum[i] += La[p][i] + Lb[p][i];
      }
      const int c = (kq + i) & 3;
      const int o = (shalf*8 + 4*c) & 15;
      unsigned* rowp = vsw + (4*kq + i)*512 + d*16;
      u32x4 lo4 = { w8[0], w8[1], w8[2], w8[3] };
      u32x4 hi4 = { w8[4], w8[5], w8[6], w8[7] };
      *(u32x4*)(rowp + o)            = lo4;
      *(u32x4*)(rowp + ((o+4)&15))   = hi4;
    }
    __syncthreads();
    // ---- prefetch next chunk during MFMA phase
    if (ch < 7) {
      const int sb = cb*256 + (ch+1)*32 + shalf*16;
      #pragma unroll
      for (int p = 0; p < 8; ++p) {
        const float* src = xb + (size_t)(sb + 2*p)*4096;
        La[p] = *(const f32x4*)src;
        Lb[p] = *(const f32x4*)(src + 4096);
      }
    }
    // ---- MFMA: 4 clusters per wave, slot-group offset (w+c)&3
    #pragma unroll
    for (int c = 0; c < 4; ++c) {
      const int kk = w*4 + c;
      const float* base = vs + kk*512;
      const int sg = 4*(((l>>4) + w + c) & 3);
      const short8 f0 = *(const short8*)(base + (l&15)*16       + sg);
      const short8 f1 = *(const short8*)(base + (l&15)*16 + 256 + sg);
      acc[c][0] = __builtin_amdgcn_mfma_f32_16x16x32_bf16(f0, f0, acc[c][0], 0,0,0);
      acc[c][1] = __builtin_amdgcn_mfma_f32_16x16x32_bf16(f0, f1, acc[c][1], 0,0,0);
      acc[c][2] = __builtin_amdgcn_mfma_f32_16x16x32_bf16(f1, f0, acc[c][2], 0,0,0);
      acc[c][3] = __builtin_amdgcn_mfma_f32_16x16x32_bf16(f1, f1, acc[c][3], 0,0,0);
    }
    __syncthreads();
  }

  // ---- epilogue: M tiles.  C/D layout col = l&15, row = (l>>4)*4 + reg.
  const int col = l & 15, rw = (l >> 4) * 4;
  #pragma unroll
  for (int c = 0; c < 4; ++c) {
    const int kg = k0 + w*4 + c;
    float* pb = part + ((size_t)cb*128 + kg)*1056;
    #pragma unroll
    for (int i = 0; i < 2; ++i)
      #pragma unroll
      for (int j = 0; j < 2; ++j)
        #pragma unroll
        for (int r = 0; r < 4; ++r)
          pb[(i*16 + rw + r)*32 + j*16 + col] = acc[c][i*2+j][r];
  }
  // ---- S: per-thread partials -> LDS -> cross-shalf reduce -> partial buf
  #pragma unroll
  for (int i = 0; i < 4; ++i)
    ssr[shalf*1024 + d*32 + 4*kq + i] = ssum[i];
  __syncthreads();
  for (int ii = t; ii < 1024; ii += 512) {
    const int dd = ii >> 5, kk2 = ii & 31;
    part[((size_t)cb*128 + k0 + kk2)*1056 + 1024 + dd] = ssr[ii] + ssr[1024 + ii];
  }
}

// ---------------------------------------------------------------------------
// Kernel 2a: reduce partials over 64 chunk-blocks.  grid 528 x 256.
// part[cb][135168], contiguous outputs -> fully coalesced; L3-resident.
// out sfin[135168] = [128 k][1056]
// ---------------------------------------------------------------------------
__global__ void k2a_reduce(const float* __restrict__ part, float* __restrict__ sfin) {
  const size_t idx = (size_t)blockIdx.x*256 + threadIdx.x;   // 0..135167
  const float* p = part + idx;
  float a0=0.f,a1=0.f,a2=0.f,a3=0.f;
  for (int c = 0; c < 64; c += 4) {
    a0 += p[(size_t)(c+0)*135168];
    a1 += p[(size_t)(c+1)*135168];
    a2 += p[(size_t)(c+2)*135168];
    a3 += p[(size_t)(c+3)*135168];
  }
  sfin[idx] = (a0+a1)+(a2+a3);
}

// ---------------------------------------------------------------------------
// Kernel 2b: per-cluster cov assembly + Cholesky.  grid 128, block 256.
// sfin[k][1056]: M (full 32x32) at d*32+e, S at 1024+d.
// ---------------------------------------------------------------------------
__global__ void k2b_chol(const float* __restrict__ sfin,
                         const float* __restrict__ mu0,
                         const float* __restrict__ L0,
                         const float* __restrict__ n0p,
                         float* __restrict__ lpad,
                         float* __restrict__ nmu) {
  const int k = blockIdx.x;
  const int t = threadIdx.x;
  __shared__ float L0s[32*33];
  __shared__ float Am[32*33];
  __shared__ float xdl[32];
  __shared__ float dinv[32];
  const float n0 = n0p[0];
  const float denom = n0 + (float)NB;
  const float* sk = sfin + (size_t)k*1056;

  for (int idx = t; idx < 1024; idx += 256)
    L0s[(idx>>5)*33 + (idx&31)] = L0[k*1024 + idx];
  if (t < 32) {
    const float S  = sk[1024 + t];
    const float m0 = mu0[t*128 + k];
    nmu[t*128 + k] = (n0*m0 + S) / denom;          // B*x_mu == S
    xdl[t] = S*(1.0f/NB) - m0;
  }
  __syncthreads();

  const float c1 = n0/denom, c2 = 1.0f/denom;
  const float c3 = n0*(float)NB/(denom*denom);
  for (int idx = t; idx < 1024; idx += 256) {
    const int d = idx>>5, e = idx&31;
    const float M  = sk[d*32 + e];
    const float Sd = sk[1024 + d];
    const float Se = sk[1024 + e];
    const float C = M - Sd*Se*(1.0f/NB);
    float g = 0.f;
    #pragma unroll 8
    for (int f=0; f<32; f++) g += L0s[d*33+f]*L0s[e*33+f];
    float a = g*c1 + C*c2 + xdl[d]*xdl[e]*c3;
    if (d==e) a += 1.0f;
    Am[d*33+e] = a;
  }
  __syncthreads();

  for (int j=0;j<32;j++){
    float acc = 0.f;
    if (t < 32 && t >= j) {
      acc = Am[t*33+j];
      for (int e=0;e<j;e++) acc -= Am[t*33+e]*Am[j*33+e];
    }
    __syncthreads();
    if (t == j) {
      const float dj = sqrtf(acc);
      Am[j*33+j] = dj;
      dinv[j] = 1.0f/dj;
    }
    __syncthreads();
    if (t < 32 && t > j) Am[t*33+j] = acc*dinv[j];
    __syncthreads();
  }

  if (t < 32) {
    const int d = t;
    int rs = 0;
    for (int e=0;e<d;e++) rs += (e+3)>>2;
    rs *= 4;
    const int rl = ((d+3)>>2)*4;
    float* lp = lpad + k*576;
    for (int e=0;e<rl;e++) lp[rs+e] = (e<d) ? Am[d*33+e] : 0.f;
    lp[544+d] = dinv[d];
  }
}

// ---------------------------------------------------------------------------
// Kernel 3 (frozen since r4, ~72us at HBM roofline): whitening solve
// z = L^{-1}(x - mu').  grid 512, block 256.  Full-128B-line accesses;
// XCD swizzle pairs ktiles (2p,2p+1) on the same XCD; NT output stores.
// ---------------------------------------------------------------------------
__global__ __launch_bounds__(256, 2) void k3_whiten(const float* __restrict__ x,
                                                    const float* __restrict__ lpad,
                                                    const float* __restrict__ nmu,
                                                    float* __restrict__ out) {
  __shared__ float Lw[32*580];   // 32 k-rows, stride 580 (16B-aligned, mod32==4)
  __shared__ float muL[32*32];   // [d][kl]
  const int t = threadIdx.x;
  const int bx = blockIdx.x;     // 0..511
  const int m = (bx >> 3) & 1;
  const int u = ((bx >> 4) << 3) | (bx & 7);   // 0..255
  const int ktile = ((u & 1) << 1) | m;        // 2p + m
  const int chunk = u >> 1;                    // 0..127
  const int k0 = ktile*32;

  {
    const f32x4* src = (const f32x4*)(lpad + (size_t)k0*576);
    #pragma unroll
    for (int q=0;q<18;q++){
      const int idx = t + q*256;        // 4608 f32x4 = 32 rows x 144
      const int row = idx/144, col = idx - row*144;
      *(f32x4*)(&Lw[row*580 + col*4]) = src[idx];
    }
    #pragma unroll
    for (int idx=t; idx<1024; idx+=256)
      muL[idx] = nmu[(idx>>5)*128 + k0 + (idx&31)];
  }
  __syncthreads();

  const int kl = t & 31;
  const int so = t >> 5;          // 0..7 sample slot
  const float* Lrow = &Lw[kl*580];
  const int b0 = chunk*128;

  for (int it=0; it<4; ++it) {
    const int base = b0 + it*32 + so;
    const float* xa = x + (size_t)(base     )*4096 + k0 + kl;
    const float* xb = x + (size_t)(base +  8)*4096 + k0 + kl;
    const float* xc = x + (size_t)(base + 16)*4096 + k0 + kl;
    const float* xd = x + (size_t)(base + 24)*4096 + k0 + kl;
    float vA[32], vB[32], vC[32], vD[32];
    #pragma unroll
    for (int d=0; d<32; ++d) vA[d] = xa[d*128];
    #pragma unroll
    for (int d=0; d<32; ++d) vB[d] = xb[d*128];
    #pragma unroll
    for (int d=0; d<32; ++d) vC[d] = xc[d*128];
    #pragma unroll
    for (int d=0; d<32; ++d) vD[d] = xd[d*128];
    #pragma unroll
    for (int d=0; d<32; ++d) {
      const float m2 = muL[d*32 + kl];
      vA[d] -= m2; vB[d] -= m2; vC[d] -= m2; vD[d] -= m2;
    }
    int rs = 0;
    #pragma unroll
    for (int d=0; d<32; ++d) {
      float sA = vA[d], sB = vB[d], sC = vC[d], sD = vD[d];
      const int nq = (d+3)>>2;
      #pragma unroll
      for (int q=0; q<nq; ++q) {
        const f32x4 Lq = *(const f32x4*)(Lrow + rs + 4*q);
        sA -= Lq[0]*vA[4*q+0] + Lq[1]*vA[4*q+1] + Lq[2]*vA[4*q+2] + Lq[3]*vA[4*q+3];
        sB -= Lq[0]*vB[4*q+0] + Lq[1]*vB[4*q+1] + Lq[2]*vB[4*q+2] + Lq[3]*vB[4*q+3];
        sC -= Lq[0]*vC[4*q+0] + Lq[1]*vC[4*q+1] + Lq[2]*vC[4*q+2] + Lq[3]*vC[4*q+3];
        sD -= Lq[0]*vD[4*q+0] + Lq[1]*vD[4*q+1] + Lq[2]*vD[4*q+2] + Lq[3]*vD[4*q+3];
      }
      const float di = Lrow[544+d];
      vA[d] = sA*di; vB[d] = sB*di; vC[d] = sC*di; vD[d] = sD*di;
      rs += 4*nq;
    }
    float* oa = out + (size_t)(base     )*4096 + k0 + kl;
    float* ob = out + (size_t)(base +  8)*4096 + k0 + kl;
    float* oc = out + (size_t)(base + 16)*4096 + k0 + kl;
    float* od = out + (size_t)(base + 24)*4096 + k0 + kl;
    #pragma unroll
    for (int d=0; d<32; ++d) __builtin_nontemporal_store(vA[d], oa + d*128);
    #pragma unroll
    for (int d=0; d<32; ++d) __builtin_nontemporal_store(vB[d], ob + d*128);
    #pragma unroll
    for (int d=0; d<32; ++d) __builtin_nontemporal_store(vC[d], oc + d*128);
    #pragma unroll
    for (int d=0; d<32; ++d) __builtin_nontemporal_store(vD[d], od + d*128);
  }
}

// ---------------------------------------------------------------------------
extern "C" void kernel_launch(void* const* d_in, const int* in_sizes, int n_in,
                              void* d_out, int out_size, void* d_ws, size_t ws_size,
                              hipStream_t stream) {
  const float* x   = (const float*)d_in[0];
  const float* mu0 = (const float*)d_in[1];
  const float* L0  = (const float*)d_in[2];
  const float* n0  = (const float*)d_in[3];
  float* out  = (float*)d_out;
  float* part = out;                    // [64][128][1056] = 8,650,752 floats (scratch in d_out)
  float* sfin = out + 8650752;          // [128][1056]     =   135,168 floats (scratch in d_out)
  float* lpad = (float*)d_ws;           // [128][576]
  float* nmu  = lpad + 128*576;         // [32][128]

  k1_scatter<<<256, 512, 0, stream>>>(x, part);
  k2a_reduce<<<528, 256, 0, stream>>>(part, sfin);
  k2b_chol  <<<128, 256, 0, stream>>>(sfin, mu0, L0, n0, lpad, nmu);
  k3_whiten <<<512, 256, 0, stream>>>(x, lpad, nmu, out);
}